// Round 1
// baseline (116.505 us; speedup 1.0000x reference)
//
#include <hip/hip_runtime.h>

// Problem shape (fixed by setup_inputs): x (16,16,64,64) f32, weight (16,64) f32, nodes (64,) f32.
constexpr int B_ = 16, F_ = 16, N_ = 64, H_ = 64, W_ = 64;
constexpr int TOTAL = B_ * F_ * H_ * W_;     // 1,048,576 elements
constexpr float LOWER = -3.0f, UPPER = 3.0f;

// One thread handles one float4 of x (4 consecutive elems share the same f since H*W=4096 % 4 == 0).
// grid = TOTAL/4/256 = 1024 blocks of 256 threads.
__global__ __launch_bounds__(256) void quartic_spline_logsum(
    const float* __restrict__ x,
    const float* __restrict__ weight,
    const float* __restrict__ nodes,
    float* __restrict__ out)
{
    __shared__ float ew[F_ * N_];   // exp(weight), 4 KiB
    __shared__ float nd[N_];

    const int tid = threadIdx.x;
    for (int i = tid; i < F_ * N_; i += 256) ew[i] = expf(weight[i]);
    if (tid < N_) nd[tid] = nodes[tid];
    __syncthreads();

    const float inv_scale = (float)(N_ - 1) / (UPPER - LOWER);  // 1/scale

    const int idx4 = blockIdx.x * 256 + tid;          // float4 index, < TOTAL/4
    const float4 v = reinterpret_cast<const float4*>(x)[idx4];
    const int base_elem = idx4 * 4;
    const int f = (base_elem >> 12) & (F_ - 1);       // /(H*W)=4096, %F
    const float* __restrict__ ewf = &ew[f * N_];

    float vals[4] = {v.x, v.y, v.z, v.w};
    float local = 0.0f;

    #pragma unroll
    for (int j = 0; j < 4; ++j) {
        const float xv = vals[j];
        // candidate node window: basis(t)=0 for |t|>=2.5; node spacing = 1 t-unit.
        // n in (u-2.5, u+2.5) subset of [floor(u)-2, floor(u)+3]  (6 candidates).
        const float u = (xv - LOWER) * inv_scale;
        const int kf = (int)floorf(u);
        const int n0 = max(0, kf - 2);
        const int n1 = min(N_ - 1, kf + 3);
        float y = 0.0f;
        for (int n = n0; n <= n1; ++n) {
            const float t  = (xv - nd[n]) * inv_scale;
            const float ta = fabsf(t);
            float r;
            if (ta < 0.5f) {
                const float z = ta + 0.5f;
                r = (11.0f + z * (12.0f + z * (-6.0f + z * (-12.0f + 6.0f * z)))) * (1.0f / 24.0f);
            } else if (ta < 1.5f) {
                const float z = 1.5f - ta;
                r = (1.0f + z * (4.0f + z * (6.0f + z * (4.0f - 4.0f * z)))) * (1.0f / 24.0f);
            } else if (ta < 2.5f) {
                float z = 2.5f - ta;
                z = z * z;
                r = z * z * (1.0f / 24.0f);
            } else {
                r = 0.0f;
            }
            y += r * ewf[n];
        }
        local += logf(y + 1e-7f);
    }

    // wave-64 butterfly reduce, then one atomic per wave (4096 atomics total).
    #pragma unroll
    for (int off = 32; off > 0; off >>= 1)
        local += __shfl_down(local, off, 64);
    if ((tid & 63) == 0)
        atomicAdd(out, local);
}

extern "C" void kernel_launch(void* const* d_in, const int* in_sizes, int n_in,
                              void* d_out, int out_size, void* d_ws, size_t ws_size,
                              hipStream_t stream) {
    const float* x      = (const float*)d_in[0];
    const float* weight = (const float*)d_in[1];
    const float* nodes  = (const float*)d_in[2];
    float* out = (float*)d_out;

    // d_out is re-poisoned to 0xAA before every timed launch — zero it on-stream.
    hipMemsetAsync(out, 0, sizeof(float), stream);

    const int threads = 256;
    const int blocks = (TOTAL / 4) / threads;  // 1024
    quartic_spline_logsum<<<blocks, threads, 0, stream>>>(x, weight, nodes, out);
}

// Round 2
// 73.837 us; speedup vs baseline: 1.5779x; 1.5779x over previous
//
#include <hip/hip_runtime.h>

// x (16,16,64,64) f32, weight (16,64) f32, nodes (64,) f32 -> scalar f32.
constexpr int B_ = 16, F_ = 16, N_ = 64, H_ = 64, W_ = 64;
constexpr int TOTAL = B_ * F_ * H_ * W_;         // 1,048,576
constexpr float LOWER = -3.0f, UPPER = 3.0f;
constexpr int THREADS = 256;
constexpr int BLOCKS  = 256;
constexpr int VEC = TOTAL / 4;                   // 262,144 float4
constexpr int PER_THREAD = VEC / (THREADS * BLOCKS);  // 4

__global__ __launch_bounds__(THREADS) void quartic_spline_logsum(
    const float* __restrict__ x,
    const float* __restrict__ weight,
    float* __restrict__ out)
{
    __shared__ float ew[F_ * N_];   // exp(weight), 4 KiB
    const int tid = threadIdx.x;
    for (int i = tid; i < F_ * N_; i += THREADS) ew[i] = __expf(weight[i]);
    __syncthreads();

    const float inv_scale = (float)(N_ - 1) / (UPPER - LOWER);  // 10.5

    float local = 0.0f;
    int idx4 = blockIdx.x * THREADS + tid;

    #pragma unroll
    for (int it = 0; it < PER_THREAD; ++it, idx4 += THREADS * BLOCKS) {
        const float4 v = reinterpret_cast<const float4*>(x)[idx4];
        // elem index = idx4*4; f = (elem >> 12) & 15 = (idx4 >> 10) & 15
        const float* __restrict__ ewf = &ew[((idx4 >> 10) & (F_ - 1)) * N_];

        const float vals[4] = {v.x, v.y, v.z, v.w};
        #pragma unroll
        for (int j = 0; j < 4; ++j) {
            const float xv = vals[j];
            const float u = (xv - LOWER) * inv_scale;   // node index in t-units
            const int kf = (int)floorf(u);
            float y = 0.0f;
            // basis(t)=0 for |t|>=2.5 and node spacing is 1 t-unit:
            // only n in [kf-2, kf+3] can contribute. Fixed 6-wide window, branchless.
            #pragma unroll
            for (int d = 0; d < 6; ++d) {
                const int n = kf - 2 + d;
                const float t  = u - (float)n;
                const float ta = fabsf(t);
                const float z0 = ta + 0.5f;
                const float r0 = 11.0f + z0 * (12.0f + z0 * (-6.0f + z0 * (-12.0f + 6.0f * z0)));
                const float z1 = 1.5f - ta;
                const float r1 = 1.0f + z1 * (4.0f + z1 * (6.0f + z1 * (4.0f - 4.0f * z1)));
                const float z2 = 2.5f - ta;
                const float z2s = z2 * z2;
                const float r2 = z2s * z2s;
                float r = ta < 0.5f ? r0 : (ta < 1.5f ? r1 : r2);
                r = (ta < 2.5f) ? r : 0.0f;
                const bool valid = ((unsigned)n < (unsigned)N_);
                const int nc = valid ? n : 0;
                r = valid ? r : 0.0f;
                y += r * ewf[nc];
            }
            local += __logf(y * (1.0f / 24.0f) + 1e-7f);
        }
    }

    // wave-64 butterfly, then LDS across the block's 4 waves, ONE atomic per block.
    #pragma unroll
    for (int off = 32; off > 0; off >>= 1)
        local += __shfl_down(local, off, 64);

    __shared__ float wpart[THREADS / 64];
    if ((tid & 63) == 0) wpart[tid >> 6] = local;
    __syncthreads();
    if (tid == 0) {
        float s = wpart[0] + wpart[1] + wpart[2] + wpart[3];
        atomicAdd(out, s);
    }
}

extern "C" void kernel_launch(void* const* d_in, const int* in_sizes, int n_in,
                              void* d_out, int out_size, void* d_ws, size_t ws_size,
                              hipStream_t stream) {
    const float* x      = (const float*)d_in[0];
    const float* weight = (const float*)d_in[1];
    float* out = (float*)d_out;

    // d_out is re-poisoned to 0xAA before every timed launch — zero it on-stream.
    hipMemsetAsync(out, 0, sizeof(float), stream);

    quartic_spline_logsum<<<BLOCKS, THREADS, 0, stream>>>(x, weight, out);
}

// Round 3
// 60.392 us; speedup vs baseline: 1.9292x; 1.2226x over previous
//
#include <hip/hip_runtime.h>

// x (16,16,64,64) f32, weight (16,64) f32, nodes (64,) f32 -> scalar f32.
constexpr int F_ = 16, N_ = 64;
constexpr int TOTAL = 16 * 16 * 64 * 64;         // 1,048,576 elements
constexpr int VEC = TOTAL / 4;                   // 262,144 float4
constexpr int THREADS = 1024;
constexpr int BLOCKS = VEC / THREADS;            // 256 blocks -> 1 float4/thread
constexpr float LOWER = -3.0f, UPPER = 3.0f;

// Closed-form 5-point quartic B-spline window.
// u = (x - LOWER)*10.5 ; s = u - rint(u) in [-0.5, 0.5]; nodes rint(u)-2 .. +2.
// w0 = p^4, w1 = 1+4p+6p^2+4p^3-4p^4, w2 = 6s^4-15s^2+14.375,
// w3 = w1(q), w4 = q^4  (p = 0.5-s, q = 0.5+s), all /24.
__global__ __launch_bounds__(THREADS) void spline_partial(
    const float* __restrict__ x,
    const float* __restrict__ weight,
    float* __restrict__ partials)
{
    __shared__ float ew[F_ * N_];   // exp(weight), 4 KiB
    const int tid = threadIdx.x;
    ew[tid] = __expf(weight[tid]);  // 1024 threads, 1024 weights
    __syncthreads();

    const int idx4 = blockIdx.x * THREADS + tid;
    const float4 v = reinterpret_cast<const float4*>(x)[idx4];
    // f = (elem>>12)&15 = (idx4>>10)&15 = blockIdx.x&15  (wave-uniform base)
    const float* __restrict__ ewf = &ew[(blockIdx.x & (F_ - 1)) * N_];

    const float vals[4] = {v.x, v.y, v.z, v.w};
    float local = 0.0f;

    #pragma unroll
    for (int j = 0; j < 4; ++j) {
        const float u = fmaf(vals[j], 10.5f, 31.5f);   // (x+3)*10.5
        const float r = rintf(u);
        const float s = u - r;                         // [-0.5, 0.5]
        const int n0 = (int)r - 2;

        const float p = 0.5f - s, q = 0.5f + s;
        const float p2 = p * p, q2 = q * q, s2 = s * s;
        float w[5];
        w[0] = p2 * p2;
        w[1] = 1.0f + p * (4.0f + p * (6.0f + p * (4.0f - 4.0f * p)));
        w[2] = fmaf(s2, fmaf(s2, 6.0f, -15.0f), 14.375f);
        w[3] = 1.0f + q * (4.0f + q * (6.0f + q * (4.0f - 4.0f * q)));
        w[4] = q2 * q2;

        float y = 0.0f;
        #pragma unroll
        for (int d = 0; d < 5; ++d) {
            const int n = n0 + d;
            const bool valid = ((unsigned)n < (unsigned)N_);
            const float wd = valid ? w[d] : 0.0f;
            y += wd * ewf[valid ? n : 0];
        }
        local += __logf(fmaf(y, 1.0f / 24.0f, 1e-7f));
    }

    // wave-64 butterfly, then LDS across the block's 16 waves.
    #pragma unroll
    for (int off = 32; off > 0; off >>= 1)
        local += __shfl_down(local, off, 64);

    __shared__ float wpart[THREADS / 64];
    if ((tid & 63) == 0) wpart[tid >> 6] = local;
    __syncthreads();
    if (tid == 0) {
        float s = 0.0f;
        #pragma unroll
        for (int i = 0; i < THREADS / 64; ++i) s += wpart[i];
        partials[blockIdx.x] = s;   // plain store; no atomics, no memset needed
    }
}

__global__ __launch_bounds__(256) void reduce_partials(
    const float* __restrict__ partials, float* __restrict__ out)
{
    const int tid = threadIdx.x;
    float v = partials[tid];        // 256 partials, 256 threads
    #pragma unroll
    for (int off = 32; off > 0; off >>= 1)
        v += __shfl_down(v, off, 64);
    __shared__ float wpart[4];
    if ((tid & 63) == 0) wpart[tid >> 6] = v;
    __syncthreads();
    if (tid == 0) out[0] = wpart[0] + wpart[1] + wpart[2] + wpart[3];
}

extern "C" void kernel_launch(void* const* d_in, const int* in_sizes, int n_in,
                              void* d_out, int out_size, void* d_ws, size_t ws_size,
                              hipStream_t stream) {
    const float* x      = (const float*)d_in[0];
    const float* weight = (const float*)d_in[1];
    float* out      = (float*)d_out;
    float* partials = (float*)d_ws;   // 256 floats of scratch

    spline_partial<<<BLOCKS, THREADS, 0, stream>>>(x, weight, partials);
    reduce_partials<<<1, 256, 0, stream>>>(partials, out);
}